// Round 15
// baseline (211.089 us; speedup 1.0000x reference)
//
#include <hip/hip_runtime.h>
#include <hip/hip_fp16.h>

#define BATCH 64
#define KSLOT 64
#define DDIM  128
#define HDIM  128
#define TTYPE 4
#define NSLOT (BATCH*KSLOT)
#define EPSLN 1e-5f
#define YROW  544   // 4*128 y + 4 wsum + 28 pad (pad killed by zero weight cols)

typedef _Float16 v8h __attribute__((ext_vector_type(8)));
typedef _Float16 v4h __attribute__((ext_vector_type(4)));
typedef _Float16 v2h __attribute__((ext_vector_type(2)));
typedef float    v4f __attribute__((ext_vector_type(4)));

__device__ __forceinline__ float waveAllSum(float v) {
    #pragma unroll
    for (int m = 1; m < 64; m <<= 1) v += __shfl_xor(v, m, 64);
    return v;
}

// ---------- k_wconv: one-time weight transpose/convert (22 blocks) ----------
__global__ __launch_bounds__(256) void k_wconv(
        const float* __restrict__ ws1, const float* __restrict__ wi1,
        const float* __restrict__ ws2, const float* __restrict__ wu1,
        const float* __restrict__ wu2, const float* __restrict__ wi3,
        const float* __restrict__ wi2, const float* __restrict__ bi1,
        const float* __restrict__ bi3,
        __half* __restrict__ ws1T, __half* __restrict__ wi1catT,
        __half* __restrict__ ws2T, __half* __restrict__ wu1T,
        __half* __restrict__ wu2T, __half* __restrict__ w3catT,
        __half* __restrict__ w2T16, float* __restrict__ biascat) {
    __shared__ __align__(16) float tile[128*132];
    int bx = blockIdx.x, tid = threadIdx.x;
    if (bx == 21) {
        for (int idx = tid; idx < 128*32; idx += 256) {
            int o = idx >> 5, c = idx & 31;
            w3catT[(size_t)o*YROW + 512 + c] = (c < 4) ? __float2half(bi3[c*DDIM + o]) : __float2half(0.f);
        }
        for (int idx = tid; idx < 1024; idx += 256) {
            int th = idx >> 7, o = idx & 127;
            biascat[idx] = (th & 1) ? bi1[(th>>1)*HDIM + o] : 0.f;
        }
        return;
    }
    const float* src; __half* dst; int dstride = 128, dcol = 0;
    if (bx == 0)      { src = ws1; dst = ws1T; }
    else if (bx <= 8) { int th = bx-1, tau = th>>1, half = th&1;
                        src = wi1 + ((size_t)tau*256 + half*128)*128;
                        dst = wi1catT + (size_t)th*128*128; }
    else if (bx == 9) { src = ws2; dst = ws2T; }
    else if (bx ==10) { src = wu2; dst = wu2T; }
    else if (bx <=12) { int hh = bx-11; src = wu1 + (size_t)hh*128*128;
                        dst = wu1T; dstride = 256; dcol = hh*128; }
    else if (bx <=16) { int tau = bx-13; src = wi3 + (size_t)tau*16384;
                        dst = w3catT; dstride = YROW; dcol = tau*128; }
    else              { int tau = bx-17; src = wi2 + (size_t)tau*16384;
                        dst = w2T16 + (size_t)tau*16384; }
    for (int idx = tid; idx < 4096; idx += 256) {
        int r = idx >> 5, c4 = idx & 31;
        *(float4*)&tile[r*132 + c4*4] = *(const float4*)&src[(size_t)r*128 + c4*4];
    }
    __syncthreads();
    for (int idx = tid; idx < 8192; idx += 256) {
        int n = idx >> 6, kp = idx & 63;
        __half2 p = __floats2half2_rn(tile[(2*kp)*132 + n], tile[(2*kp+1)*132 + n]);
        *(__half2*)&dst[(size_t)n*dstride + dcol + 2*kp] = p;
    }
}

// ---------- k_pair: fused wi1-projection + pair GEMM (R11-proven i-loop, inline wS) ----------
#define LROW 136
__global__ __launch_bounds__(512) void k_pair(
        const float* __restrict__ h,        // [4096][128] fp32
        const __half* __restrict__ wi1catT, // [8][128 o][128 k]
        const float* __restrict__ biascat,  // [8*128]
        const __half* __restrict__ w2T16,   // [4][128][128]
        const float* __restrict__ bi2,
        const float* __restrict__ ep, const float* __restrict__ et,
        __half* __restrict__ Ycat) {        // [4096][YROW]
    __shared__ __align__(16) _Float16 w2T[HDIM*LROW];   // 34816
    __shared__ __align__(16) _Float16 Cs[KSLOT*LROW];   // 17408
    __shared__ __align__(16) _Float16 As[KSLOT*LROW];   // 17408
    __shared__ __align__(16) _Float16 wS[KSLOT*KSLOT];  //  8192
    __shared__ __align__(16) _Float16 hs[KSLOT*136];    // 17408 -> 95232 B
    int bx = blockIdx.x, b = bx >> 2, tau = bx & 3;
    int tid = threadIdx.x, lane = tid & 63, w = tid >> 6;
    int jt = w >> 1, oh = w & 1, quad = lane >> 4, n = lane & 15;

    for (int idx = tid; idx < 2048; idx += 512) {
        int o = idx >> 4, seg = (idx & 15)*8;
        *(v8h*)&w2T[o*LROW + seg] = *(const v8h*)&w2T16[((size_t)tau*128 + o)*128 + seg];
    }
    {
        int row = tid >> 3, c0 = (tid & 7)*16;
        const float* hp = &h[(size_t)(b*KSLOT + row)*128 + c0];
        #pragma unroll
        for (int q = 0; q < 4; q++) {
            float4 f = *(const float4*)&hp[q*4];
            *(__half2*)&hs[row*136 + c0 + q*4]     = __floats2half2_rn(f.x, f.y);
            *(__half2*)&hs[row*136 + c0 + q*4 + 2] = __floats2half2_rn(f.z, f.w);
        }
    }
    {   // wS = f16(ep * et[...,tau]) inline (time-neutral vs precompute: R7 vs R8)
        const float* epb = ep + (size_t)b*4096;
        const float* etb = et + (size_t)b*4096*TTYPE + tau;
        int base = tid*8;
        #pragma unroll
        for (int q = 0; q < 8; q += 2) {
            float e0 = epb[base+q]   * etb[(size_t)(base+q)*TTYPE];
            float e1 = epb[base+q+1] * etb[(size_t)(base+q+1)*TTYPE];
            *(v2h*)&wS[base+q] = __builtin_bit_cast(v2h, __builtin_amdgcn_cvt_pkrtz(e0, e1));
        }
    }
    __syncthreads();

    // phase 1: As/Cs = hs @ wi1[tau] (+bias on C)
    {
        int hf = w >> 2, rt = w & 3;
        const __half* wb = wi1catT + (size_t)(tau*2 + hf)*128*128;
        const float* bcp = biascat + (tau*2 + hf)*128;
        _Float16* dst = hf ? Cs : As;
        v8h afr[4];
        #pragma unroll
        for (int ks = 0; ks < 4; ks++)
            afr[ks] = *(const v8h*)&hs[(rt*16 + n)*136 + ks*32 + quad*8];
        #pragma unroll
        for (int ot = 0; ot < 8; ot++) {
            float b0 = bcp[ot*16 + n];
            v4f acc = (v4f){b0, b0, b0, b0};
            #pragma unroll
            for (int ks = 0; ks < 4; ks++)
                acc = __builtin_amdgcn_mfma_f32_16x16x32_f16(
                    afr[ks], *(const v8h*)&wb[(size_t)(ot*16 + n)*128 + ks*32 + quad*8], acc, 0, 0, 0);
            #pragma unroll
            for (int r = 0; r < 4; r++)
                dst[(rt*16 + quad*4 + r)*LROW + ot*16 + n] = (_Float16)acc[r];
        }
    }
    __syncthreads();

    // phase 2: i-loop (R11-proven form)
    v8h bfrag[4][4];
    #pragma unroll
    for (int ot = 0; ot < 4; ot++)
        #pragma unroll
        for (int ks = 0; ks < 4; ks++)
            bfrag[ot][ks] = *(const v8h*)&w2T[(oh*64 + ot*16 + n)*LROW + ks*32 + quad*8];
    v8h cfrag[4];
    #pragma unroll
    for (int ks = 0; ks < 4; ks++)
        cfrag[ks] = *(const v8h*)&Cs[(jt*16 + n)*LROW + ks*32 + quad*8];
    v4f biasvec[4];
    #pragma unroll
    for (int ot = 0; ot < 4; ot++) {
        float b0 = bi2[tau*HDIM + oh*64 + ot*16 + n];
        biasvec[ot] = (v4f){b0, b0, b0, b0};
    }

    v4h yacch[4];
    #pragma unroll
    for (int ot = 0; ot < 4; ot++) yacch[ot] = (v4h){0,0,0,0};
    v4h wsacch = (v4h){0,0,0,0};
    const v8h zero8 = {0,0,0,0,0,0,0,0};
    const v4h zero4h = {0,0,0,0};

    v8h aN[4]; v4h wvN;
    #pragma unroll
    for (int ks = 0; ks < 4; ks++) aN[ks] = *(const v8h*)&As[ks*32 + quad*8];
    wvN = *(const v4h*)&wS[jt*16 + quad*4];

    for (int i = 0; i < KSLOT; ++i) {
        v8h a[4]; v4h wv = wvN;
        #pragma unroll
        for (int ks = 0; ks < 4; ks++) a[ks] = aN[ks];
        if (i < KSLOT-1) {
            #pragma unroll
            for (int ks = 0; ks < 4; ks++)
                aN[ks] = *(const v8h*)&As[(i+1)*LROW + ks*32 + quad*8];
            wvN = *(const v4h*)&wS[(i+1)*KSLOT + jt*16 + quad*4];
        }
        v8h x1[4];
        #pragma unroll
        for (int ks = 0; ks < 4; ks++)
            x1[ks] = __builtin_elementwise_max(a[ks] + cfrag[ks], zero8);
        #pragma unroll
        for (int ot = 0; ot < 4; ot++) {
            v4f acc = __builtin_amdgcn_mfma_f32_16x16x32_f16(x1[0], bfrag[ot][0], biasvec[ot], 0, 0, 0);
            #pragma unroll
            for (int ks = 1; ks < 4; ks++)
                acc = __builtin_amdgcn_mfma_f32_16x16x32_f16(x1[ks], bfrag[ot][ks], acc, 0, 0, 0);
            v2h lo = __builtin_bit_cast(v2h, __builtin_amdgcn_cvt_pkrtz(acc[0], acc[1]));
            v2h hi = __builtin_bit_cast(v2h, __builtin_amdgcn_cvt_pkrtz(acc[2], acc[3]));
            v4h rel = {lo[0], lo[1], hi[0], hi[1]};
            rel = __builtin_elementwise_max(rel, zero4h);
            yacch[ot] = yacch[ot] + wv * rel;
        }
        wsacch = wsacch + wv;
    }

    #pragma unroll
    for (int r = 0; r < 4; r++) {
        int j = jt*16 + quad*4 + r;
        __half* yb = Ycat + (size_t)(b*KSLOT + j)*YROW + tau*128 + oh*64;
        #pragma unroll
        for (int ot = 0; ot < 4; ot++)
            yb[ot*16 + n] = __float2half((float)yacch[ot][r]);
    }
    if (oh == 0 && n == 0) {
        #pragma unroll
        for (int r = 0; r < 4; r++)
            Ycat[(size_t)(b*KSLOT + jt*16 + quad*4 + r)*YROW + 512 + tau] = __float2half((float)wsacch[r]);
    }
}

// ---------- k_mega: f_self chain + dinter GEMM + LN(256) + update MLP + residual ----------
__global__ __launch_bounds__(512, 1) void k_mega(
        const __half* __restrict__ Ycat, const __half* __restrict__ w3catT,
        const float* __restrict__ ls_g, const float* __restrict__ ls_b,
        const __half* __restrict__ ws1T, const float* __restrict__ bs1,
        const __half* __restrict__ ws2T, const float* __restrict__ bs2,
        const float* __restrict__ g, const float* __restrict__ bb,
        const __half* __restrict__ wu1T, const float* __restrict__ bu1,
        const __half* __restrict__ wu2T, const float* __restrict__ bu2,
        const float* __restrict__ h, float* __restrict__ hout) {
    __shared__ __align__(16) _Float16 Ys[16*552];    // 17664
    __shared__ __align__(16) float    Crow[16*260];  // 16640
    __shared__ __align__(16) float    Hrow[16*132];  //  8448
    __shared__ __align__(16) _Float16 Xs[16*136];    //  4352
    __shared__ __align__(16) _Float16 Ts[16*136];    //  4352
    __shared__ __align__(16) _Float16 Xa[16*264];    //  8448
    __shared__ __align__(16) _Float16 Ut[16*136];    //  4352  -> 64256 B
    int tid = threadIdx.x, lane = tid & 63, w = tid >> 6;
    int n = lane & 15, quad = lane >> 4;
    int row0 = blockIdx.x*16;
    const v4f zero4f = (v4f){0.f,0.f,0.f,0.f};
    v8h f3[17];
    #pragma unroll
    for (int ks = 0; ks < 17; ks++)
        f3[ks] = *(const v8h*)&w3catT[(size_t)(w*16 + n)*YROW + ks*32 + quad*8];
    v8h f1[8];
    #pragma unroll
    for (int ks = 0; ks < 8; ks++)
        f1[ks] = *(const v8h*)&wu1T[(size_t)(w*16 + n)*256 + ks*32 + quad*8];
    v8h f2[4], fs1[4], fs2[4];
    #pragma unroll
    for (int ks = 0; ks < 4; ks++) {
        f2[ks]  = *(const v8h*)&wu2T[(size_t)(w*16 + n)*128 + ks*32 + quad*8];
        fs1[ks] = *(const v8h*)&ws1T[(size_t)(w*16 + n)*128 + ks*32 + quad*8];
        fs2[ks] = *(const v8h*)&ws2T[(size_t)(w*16 + n)*128 + ks*32 + quad*8];
    }

    for (int u = tid; u < 1024; u += 512) {
        int r = u >> 6, seg = (u & 63)*8;
        *(v8h*)&Ys[r*552 + seg] = *(const v8h*)&Ycat[(size_t)(row0 + r)*YROW + seg];
    }
    if (tid < 64) {
        int r = tid >> 2, seg = 512 + (tid & 3)*8;
        *(v8h*)&Ys[r*552 + seg] = *(const v8h*)&Ycat[(size_t)(row0 + r)*YROW + seg];
    }
    {
        int r = tid >> 5, c4 = (tid & 31)*4;
        *(float4*)&Hrow[r*132 + c4] = *(const float4*)&h[(size_t)(row0 + r)*128 + c4];
    }
    __syncthreads();
    // dinter -> Crow[:,128:256]  (split 9+8 chains)
    {
        v4f accA = zero4f, accB = zero4f;
        #pragma unroll
        for (int ks = 0; ks < 8; ks++) {
            v8h aA = *(const v8h*)&Ys[n*552 + ks*32 + quad*8];
            v8h aB = *(const v8h*)&Ys[n*552 + (ks+8)*32 + quad*8];
            accA = __builtin_amdgcn_mfma_f32_16x16x32_f16(aA, f3[ks], accA, 0, 0, 0);
            accB = __builtin_amdgcn_mfma_f32_16x16x32_f16(aB, f3[ks+8], accB, 0, 0, 0);
        }
        {
            v8h aA = *(const v8h*)&Ys[n*552 + 16*32 + quad*8];
            accA = __builtin_amdgcn_mfma_f32_16x16x32_f16(aA, f3[16], accA, 0, 0, 0);
        }
        v4f acc = accA + accB;
        #pragma unroll
        for (int r = 0; r < 4; r++)
            Crow[(quad*4 + r)*260 + 128 + w*16 + n] = acc[r];
    }
    // LN(128) of h -> Xs
    #pragma unroll
    for (int rr = 0; rr < 2; rr++) {
        int r = w*2 + rr;
        float x0 = Hrow[r*132 + 2*lane], x1 = Hrow[r*132 + 2*lane + 1];
        float mu = waveAllSum(x0 + x1) * (1.f/128.f);
        float d0 = x0 - mu, d1 = x1 - mu;
        float var = waveAllSum(d0*d0 + d1*d1) * (1.f/128.f);
        float rs = rsqrtf(var + EPSLN);
        float2 gv = *(const float2*)&ls_g[2*lane];
        float2 bv = *(const float2*)&ls_b[2*lane];
        *(__half2*)&Xs[r*136 + 2*lane] = __floats2half2_rn(d0*rs*gv.x + bv.x, d1*rs*gv.y + bv.y);
    }
    __syncthreads();
    // t = relu(Xs @ ws1 + bs1)
    {
        float b0 = bs1[w*16 + n];
        v4f accA = (v4f){b0, b0, b0, b0}, accB = zero4f;
        #pragma unroll
        for (int ks = 0; ks < 2; ks++) {
            v8h aA = *(const v8h*)&Xs[n*136 + ks*32 + quad*8];
            v8h aB = *(const v8h*)&Xs[n*136 + (ks+2)*32 + quad*8];
            accA = __builtin_amdgcn_mfma_f32_16x16x32_f16(aA, fs1[ks], accA, 0, 0, 0);
            accB = __builtin_amdgcn_mfma_f32_16x16x32_f16(aB, fs1[ks+2], accB, 0, 0, 0);
        }
        v4f acc = accA + accB;
        #pragma unroll
        for (int r = 0; r < 4; r++)
            Ts[(quad*4 + r)*136 + w*16 + n] = (_Float16)fmaxf(acc[r], 0.f);
    }
    __syncthreads();
    // Crow[:,0:128] = h + t @ ws2 + bs2
    {
        float b0 = bs2[w*16 + n];
        v4f accA = (v4f){b0, b0, b0, b0}, accB = zero4f;
        #pragma unroll
        for (int ks = 0; ks < 2; ks++) {
            v8h aA = *(const v8h*)&Ts[n*136 + ks*32 + quad*8];
            v8h aB = *(const v8h*)&Ts[n*136 + (ks+2)*32 + quad*8];
            accA = __builtin_amdgcn_mfma_f32_16x16x32_f16(aA, fs2[ks], accA, 0, 0, 0);
            accB = __builtin_amdgcn_mfma_f32_16x16x32_f16(aB, fs2[ks+2], accB, 0, 0, 0);
        }
        v4f acc = accA + accB;
        #pragma unroll
        for (int r = 0; r < 4; r++) {
            int rr = quad*4 + r, col = w*16 + n;
            Crow[rr*260 + col] = Hrow[rr*132 + col] + acc[r];
        }
    }
    __syncthreads();
    // LN(256) -> Xa
    #pragma unroll
    for (int rr = 0; rr < 2; rr++) {
        int r = w*2 + rr;
        float4 v = *(const float4*)&Crow[r*260 + 4*lane];
        float mu = waveAllSum(v.x + v.y + v.z + v.w) * (1.f/256.f);
        float d0 = v.x-mu, d1 = v.y-mu, d2 = v.z-mu, d3 = v.w-mu;
        float var = waveAllSum(d0*d0 + d1*d1 + d2*d2 + d3*d3) * (1.f/256.f);
        float rs = rsqrtf(var + EPSLN);
        float4 gv = *(const float4*)&g[4*lane];
        float4 bv = *(const float4*)&bb[4*lane];
        *(__half2*)&Xa[r*264 + 4*lane]     = __floats2half2_rn(d0*rs*gv.x + bv.x, d1*rs*gv.y + bv.y);
        *(__half2*)&Xa[r*264 + 4*lane + 2] = __floats2half2_rn(d2*rs*gv.z + bv.z, d3*rs*gv.w + bv.w);
    }
    __syncthreads();
    // u = relu(Xa @ wu1 + bu1)  (split 4+4)
    {
        float b0 = bu1[w*16 + n];
        v4f accA = (v4f){b0, b0, b0, b0}, accB = zero4f;
        #pragma unroll
        for (int ks = 0; ks < 4; ks++) {
            v8h aA = *(const v8h*)&Xa[n*264 + ks*32 + quad*8];
            v8h aB = *(const v8h*)&Xa[n*264 + (ks+4)*32 + quad*8];
            accA = __builtin_amdgcn_mfma_f32_16x16x32_f16(aA, f1[ks], accA, 0, 0, 0);
            accB = __builtin_amdgcn_mfma_f32_16x16x32_f16(aB, f1[ks+4], accB, 0, 0, 0);
        }
        v4f acc = accA + accB;
        #pragma unroll
        for (int r = 0; r < 4; r++)
            Ut[(quad*4 + r)*136 + w*16 + n] = (_Float16)fmaxf(acc[r], 0.f);
    }
    __syncthreads();
    // hout = h + u @ wu2 + bu2
    {
        float b0 = bu2[w*16 + n];
        v4f accA = (v4f){b0, b0, b0, b0}, accB = zero4f;
        #pragma unroll
        for (int ks = 0; ks < 2; ks++) {
            v8h aA = *(const v8h*)&Ut[n*136 + ks*32 + quad*8];
            v8h aB = *(const v8h*)&Ut[n*136 + (ks+2)*32 + quad*8];
            accA = __builtin_amdgcn_mfma_f32_16x16x32_f16(aA, f2[ks], accA, 0, 0, 0);
            accB = __builtin_amdgcn_mfma_f32_16x16x32_f16(aB, f2[ks+2], accB, 0, 0, 0);
        }
        v4f acc = accA + accB;
        #pragma unroll
        for (int r = 0; r < 4; r++) {
            int rr = quad*4 + r, col = w*16 + n;
            hout[(size_t)(row0 + rr)*128 + col] = Hrow[rr*132 + col] + acc[r];
        }
    }
}

// ---------- launch ----------
extern "C" void kernel_launch(void* const* d_in, const int* in_sizes, int n_in,
                              void* d_out, int out_size, void* d_ws, size_t ws_size,
                              hipStream_t stream) {
    const float* slots = (const float*)d_in[0];
    const float* ep    = (const float*)d_in[1];
    const float* et    = (const float*)d_in[2];
    const float* ls_g  = (const float*)d_in[3];
    const float* ls_b  = (const float*)d_in[4];
    const float* ws1   = (const float*)d_in[5];
    const float* bs1   = (const float*)d_in[6];
    const float* ws2   = (const float*)d_in[7];
    const float* bs2   = (const float*)d_in[8];
    const float* wi1   = (const float*)d_in[9];
    const float* bi1   = (const float*)d_in[10];
    const float* wi2   = (const float*)d_in[11];
    const float* bi2   = (const float*)d_in[12];
    const float* wi3   = (const float*)d_in[13];
    const float* bi3   = (const float*)d_in[14];
    const float* lu_g  = (const float*)d_in[15];
    const float* lu_b  = (const float*)d_in[16];
    const float* wu1   = (const float*)d_in[17];
    const float* bu1   = (const float*)d_in[18];
    const float* wu2   = (const float*)d_in[19];
    const float* bu2   = (const float*)d_in[20];
    float* out = (float*)d_out;

    char* p = (char*)d_ws;
    float*  h_buf   = (float*)p;   p += (size_t)NSLOT*DDIM*4;
    __half* Ycat    = (__half*)p;  p += (size_t)NSLOT*YROW*2;
    __half* ws1T    = (__half*)p;  p += 128*128*2;
    __half* wi1catT = (__half*)p;  p += 1024*128*2;
    __half* ws2T    = (__half*)p;  p += 128*128*2;
    __half* wu1T    = (__half*)p;  p += 128*256*2;
    __half* wu2T    = (__half*)p;  p += 128*128*2;
    __half* w3catT  = (__half*)p;  p += 128*YROW*2;
    __half* w2T16   = (__half*)p;  p += 4*128*128*2;
    float*  biascat = (float*)p;   p += 1024*4;

    k_wconv<<<22, 256, 0, stream>>>(ws1, wi1, ws2, wu1, wu2, wi3, wi2, bi1, bi3,
                                    ws1T, wi1catT, ws2T, wu1T, wu2T,
                                    w3catT, w2T16, biascat);

    for (int mp = 0; mp < 2; mp++) {
        const float* h = (mp == 0) ? slots : h_buf;
        float* hout = (mp == 0) ? h_buf : out;
        k_pair<<<BATCH*TTYPE, 512, 0, stream>>>(h, wi1catT, biascat, w2T16, bi2, ep, et, Ycat);
        k_mega<<<NSLOT/16, 512, 0, stream>>>(Ycat, w3catT, ls_g, ls_b, ws1T, bs1, ws2T, bs2,
                                             lu_g, lu_b, wu1T, bu1, wu2T, bu2, h, hout);
    }
}

// Round 17
// 205.212 us; speedup vs baseline: 1.0286x; 1.0286x over previous
//
#include <hip/hip_runtime.h>
#include <hip/hip_fp16.h>

#define BATCH 64
#define KSLOT 64
#define DDIM  128
#define HDIM  128
#define TTYPE 4
#define NSLOT (BATCH*KSLOT)
#define EPSLN 1e-5f
#define YROW  544   // 4*128 y + 4 wsum + 28 pad (pad killed by zero weight cols)

typedef _Float16 v8h __attribute__((ext_vector_type(8)));
typedef _Float16 v4h __attribute__((ext_vector_type(4)));
typedef _Float16 v2h __attribute__((ext_vector_type(2)));
typedef float    v4f __attribute__((ext_vector_type(4)));

__device__ __forceinline__ float waveAllSum(float v) {
    #pragma unroll
    for (int m = 1; m < 64; m <<= 1) v += __shfl_xor(v, m, 64);
    return v;
}

// ---------- k_wconv: one-time weight transpose/convert + w-precompute ----------
__global__ __launch_bounds__(256) void k_wconv(
        const float* __restrict__ ws1, const float* __restrict__ wi1,
        const float* __restrict__ ws2, const float* __restrict__ wu1,
        const float* __restrict__ wu2, const float* __restrict__ wi3,
        const float* __restrict__ wi2, const float* __restrict__ bi1,
        const float* __restrict__ bi3,
        const float* __restrict__ ep, const float* __restrict__ et,
        __half* __restrict__ ws1T, __half* __restrict__ wi1catT,
        __half* __restrict__ ws2T, __half* __restrict__ wu1T,
        __half* __restrict__ wu2T, __half* __restrict__ w3catT,
        __half* __restrict__ w2T16, float* __restrict__ biascat,
        __half* __restrict__ wPre) {
    __shared__ __align__(16) float tile[128*132];
    int bx = blockIdx.x, tid = threadIdx.x;
    if (bx >= 22) {
        int bx2 = bx - 22, tau = bx2 & 3, b = bx2 >> 2;
        const float* epb = ep + (size_t)b*4096;
        const float* etb = et + (size_t)b*4096*TTYPE + tau;
        __half* dst = wPre + ((size_t)tau*BATCH + b)*4096;
        for (int idx = tid; idx < 4096; idx += 256)
            dst[idx] = __float2half(epb[idx] * etb[(size_t)idx*TTYPE]);
        return;
    }
    if (bx == 21) {
        for (int idx = tid; idx < 128*32; idx += 256) {
            int o = idx >> 5, c = idx & 31;
            w3catT[(size_t)o*YROW + 512 + c] = (c < 4) ? __float2half(bi3[c*DDIM + o]) : __float2half(0.f);
        }
        for (int idx = tid; idx < 1024; idx += 256) {
            int th = idx >> 7, o = idx & 127;
            biascat[idx] = (th & 1) ? bi1[(th>>1)*HDIM + o] : 0.f;
        }
        return;
    }
    const float* src; __half* dst; int dstride = 128, dcol = 0;
    if (bx == 0)      { src = ws1; dst = ws1T; }
    else if (bx <= 8) { int th = bx-1, tau = th>>1, half = th&1;
                        src = wi1 + ((size_t)tau*256 + half*128)*128;
                        dst = wi1catT + (size_t)th*128*128; }
    else if (bx == 9) { src = ws2; dst = ws2T; }
    else if (bx ==10) { src = wu2; dst = wu2T; }
    else if (bx <=12) { int hh = bx-11; src = wu1 + (size_t)hh*128*128;
                        dst = wu1T; dstride = 256; dcol = hh*128; }
    else if (bx <=16) { int tau = bx-13; src = wi3 + (size_t)tau*16384;
                        dst = w3catT; dstride = YROW; dcol = tau*128; }
    else              { int tau = bx-17; src = wi2 + (size_t)tau*16384;
                        dst = w2T16 + (size_t)tau*16384; }
    for (int idx = tid; idx < 4096; idx += 256) {
        int r = idx >> 5, c4 = idx & 31;
        *(float4*)&tile[r*132 + c4*4] = *(const float4*)&src[(size_t)r*128 + c4*4];
    }
    __syncthreads();
    for (int idx = tid; idx < 8192; idx += 256) {
        int n = idx >> 6, kp = idx & 63;
        __half2 p = __floats2half2_rn(tile[(2*kp)*132 + n], tile[(2*kp+1)*132 + n]);
        *(__half2*)&dst[(size_t)n*dstride + dcol + 2*kp] = p;
    }
}

// ---------- k_pair: fused wi1-projection + pair GEMM (R11-proven, 44.7 us) ----------
#define LROW 136
__global__ __launch_bounds__(512) void k_pair(
        const float* __restrict__ h,        // [4096][128] fp32
        const __half* __restrict__ wi1catT, // [8][128 o][128 k]
        const float* __restrict__ biascat,  // [8*128]
        const __half* __restrict__ w2T16,   // [4][128][128]
        const float* __restrict__ bi2,
        const __half* __restrict__ wPre,    // [4][64][64][64] f16
        __half* __restrict__ Ycat) {        // [4096][YROW]
    __shared__ __align__(16) _Float16 w2T[HDIM*LROW];   // 34816
    __shared__ __align__(16) _Float16 Cs[KSLOT*LROW];   // 17408
    __shared__ __align__(16) _Float16 As[KSLOT*LROW];   // 17408
    __shared__ __align__(16) _Float16 wS[KSLOT*KSLOT];  //  8192
    __shared__ __align__(16) _Float16 hs[KSLOT*136];    // 17408 -> 95232 B
    int bx = blockIdx.x, b = bx >> 2, tau = bx & 3;
    int tid = threadIdx.x, lane = tid & 63, w = tid >> 6;
    int jt = w >> 1, oh = w & 1, quad = lane >> 4, n = lane & 15;

    for (int idx = tid; idx < 2048; idx += 512) {
        int o = idx >> 4, seg = (idx & 15)*8;
        *(v8h*)&w2T[o*LROW + seg] = *(const v8h*)&w2T16[((size_t)tau*128 + o)*128 + seg];
    }
    {
        int row = tid >> 3, c0 = (tid & 7)*16;
        const float* hp = &h[(size_t)(b*KSLOT + row)*128 + c0];
        #pragma unroll
        for (int q = 0; q < 4; q++) {
            float4 f = *(const float4*)&hp[q*4];
            *(__half2*)&hs[row*136 + c0 + q*4]     = __floats2half2_rn(f.x, f.y);
            *(__half2*)&hs[row*136 + c0 + q*4 + 2] = __floats2half2_rn(f.z, f.w);
        }
    }
    {
        int base = tid*8;
        *(v8h*)&wS[base] = *(const v8h*)&wPre[((size_t)tau*BATCH + b)*4096 + base];
    }
    __syncthreads();

    // phase 1: As/Cs = hs @ wi1[tau] (+bias on C)
    {
        int hf = w >> 2, rt = w & 3;
        const __half* wb = wi1catT + (size_t)(tau*2 + hf)*128*128;
        const float* bcp = biascat + (tau*2 + hf)*128;
        _Float16* dst = hf ? Cs : As;
        v8h afr[4];
        #pragma unroll
        for (int ks = 0; ks < 4; ks++)
            afr[ks] = *(const v8h*)&hs[(rt*16 + n)*136 + ks*32 + quad*8];
        #pragma unroll
        for (int ot = 0; ot < 8; ot++) {
            float b0 = bcp[ot*16 + n];
            v4f acc = (v4f){b0, b0, b0, b0};
            #pragma unroll
            for (int ks = 0; ks < 4; ks++)
                acc = __builtin_amdgcn_mfma_f32_16x16x32_f16(
                    afr[ks], *(const v8h*)&wb[(size_t)(ot*16 + n)*128 + ks*32 + quad*8], acc, 0, 0, 0);
            #pragma unroll
            for (int r = 0; r < 4; r++)
                dst[(rt*16 + quad*4 + r)*LROW + ot*16 + n] = (_Float16)acc[r];
        }
    }
    __syncthreads();

    // phase 2: i-loop
    v8h bfrag[4][4];
    #pragma unroll
    for (int ot = 0; ot < 4; ot++)
        #pragma unroll
        for (int ks = 0; ks < 4; ks++)
            bfrag[ot][ks] = *(const v8h*)&w2T[(oh*64 + ot*16 + n)*LROW + ks*32 + quad*8];
    v8h cfrag[4];
    #pragma unroll
    for (int ks = 0; ks < 4; ks++)
        cfrag[ks] = *(const v8h*)&Cs[(jt*16 + n)*LROW + ks*32 + quad*8];
    v4f biasvec[4];
    #pragma unroll
    for (int ot = 0; ot < 4; ot++) {
        float b0 = bi2[tau*HDIM + oh*64 + ot*16 + n];
        biasvec[ot] = (v4f){b0, b0, b0, b0};
    }

    v4h yacch[4];
    #pragma unroll
    for (int ot = 0; ot < 4; ot++) yacch[ot] = (v4h){0,0,0,0};
    v4h wsacch = (v4h){0,0,0,0};
    const v8h zero8 = {0,0,0,0,0,0,0,0};
    const v4h zero4h = {0,0,0,0};

    v8h aN[4]; v4h wvN;
    #pragma unroll
    for (int ks = 0; ks < 4; ks++) aN[ks] = *(const v8h*)&As[ks*32 + quad*8];
    wvN = *(const v4h*)&wS[jt*16 + quad*4];

    for (int i = 0; i < KSLOT; ++i) {
        v8h a[4]; v4h wv = wvN;
        #pragma unroll
        for (int ks = 0; ks < 4; ks++) a[ks] = aN[ks];
        if (i < KSLOT-1) {
            #pragma unroll
            for (int ks = 0; ks < 4; ks++)
                aN[ks] = *(const v8h*)&As[(i+1)*LROW + ks*32 + quad*8];
            wvN = *(const v4h*)&wS[(i+1)*KSLOT + jt*16 + quad*4];
        }
        v8h x1[4];
        #pragma unroll
        for (int ks = 0; ks < 4; ks++)
            x1[ks] = __builtin_elementwise_max(a[ks] + cfrag[ks], zero8);
        #pragma unroll
        for (int ot = 0; ot < 4; ot++) {
            v4f acc = __builtin_amdgcn_mfma_f32_16x16x32_f16(x1[0], bfrag[ot][0], biasvec[ot], 0, 0, 0);
            #pragma unroll
            for (int ks = 1; ks < 4; ks++)
                acc = __builtin_amdgcn_mfma_f32_16x16x32_f16(x1[ks], bfrag[ot][ks], acc, 0, 0, 0);
            v2h lo = __builtin_bit_cast(v2h, __builtin_amdgcn_cvt_pkrtz(acc[0], acc[1]));
            v2h hi = __builtin_bit_cast(v2h, __builtin_amdgcn_cvt_pkrtz(acc[2], acc[3]));
            v4h rel = {lo[0], lo[1], hi[0], hi[1]};
            rel = __builtin_elementwise_max(rel, zero4h);
            yacch[ot] = yacch[ot] + wv * rel;
        }
        wsacch = wsacch + wv;
    }

    #pragma unroll
    for (int r = 0; r < 4; r++) {
        int j = jt*16 + quad*4 + r;
        __half* yb = Ycat + (size_t)(b*KSLOT + j)*YROW + tau*128 + oh*64;
        #pragma unroll
        for (int ot = 0; ot < 4; ot++)
            yb[ot*16 + n] = __float2half((float)yacch[ot][r]);
    }
    if (oh == 0 && n == 0) {
        #pragma unroll
        for (int r = 0; r < 4; r++)
            Ycat[(size_t)(b*KSLOT + jt*16 + quad*4 + r)*YROW + 512 + tau] = __float2half((float)wsacch[r]);
    }
}

// ---------- k_mega: f_self chain + dinter GEMM + LN(256) + update MLP + residual ----------
__global__ __launch_bounds__(512, 1) void k_mega(
        const __half* __restrict__ Ycat, const __half* __restrict__ w3catT,
        const float* __restrict__ ls_g, const float* __restrict__ ls_b,
        const __half* __restrict__ ws1T, const float* __restrict__ bs1,
        const __half* __restrict__ ws2T, const float* __restrict__ bs2,
        const float* __restrict__ g, const float* __restrict__ bb,
        const __half* __restrict__ wu1T, const float* __restrict__ bu1,
        const __half* __restrict__ wu2T, const float* __restrict__ bu2,
        const float* __restrict__ h, float* __restrict__ hout) {
    __shared__ __align__(16) _Float16 Ys[16*552];    // 17664
    __shared__ __align__(16) float    Crow[16*260];  // 16640
    __shared__ __align__(16) float    Hrow[16*132];  //  8448
    __shared__ __align__(16) _Float16 Xs[16*136];    //  4352
    __shared__ __align__(16) _Float16 Ts[16*136];    //  4352
    __shared__ __align__(16) _Float16 Xa[16*264];    //  8448
    __shared__ __align__(16) _Float16 Ut[16*136];    //  4352  -> 64256 B
    int tid = threadIdx.x, lane = tid & 63, w = tid >> 6;
    int n = lane & 15, quad = lane >> 4;
    int row0 = blockIdx.x*16;
    // preload weight fragments (L2 latency hides under staging)
    v8h f3[17];
    #pragma unroll
    for (int ks = 0; ks < 17; ks++)
        f3[ks] = *(const v8h*)&w3catT[(size_t)(w*16 + n)*YROW + ks*32 + quad*8];
    v8h f1[8];
    #pragma unroll
    for (int ks = 0; ks < 8; ks++)
        f1[ks] = *(const v8h*)&wu1T[(size_t)(w*16 + n)*256 + ks*32 + quad*8];
    v8h f2[4], fs1[4], fs2[4];
    #pragma unroll
    for (int ks = 0; ks < 4; ks++) {
        f2[ks]  = *(const v8h*)&wu2T[(size_t)(w*16 + n)*128 + ks*32 + quad*8];
        fs1[ks] = *(const v8h*)&ws1T[(size_t)(w*16 + n)*128 + ks*32 + quad*8];
        fs2[ks] = *(const v8h*)&ws2T[(size_t)(w*16 + n)*128 + ks*32 + quad*8];
    }

    for (int u = tid; u < 1024; u += 512) {
        int r = u >> 6, seg = (u & 63)*8;
        *(v8h*)&Ys[r*552 + seg] = *(const v8h*)&Ycat[(size_t)(row0 + r)*YROW + seg];
    }
    if (tid < 64) {
        int r = tid >> 2, seg = 512 + (tid & 3)*8;
        *(v8h*)&Ys[r*552 + seg] = *(const v8h*)&Ycat[(size_t)(row0 + r)*YROW + seg];
    }
    {
        int r = tid >> 5, c4 = (tid & 31)*4;
        *(float4*)&Hrow[r*132 + c4] = *(const float4*)&h[(size_t)(row0 + r)*128 + c4];
    }
    __syncthreads();
    // dinter = Ys @ w3catT^T  -> Crow[:,128:256]
    {
        v4f acc = (v4f){0.f,0.f,0.f,0.f};
        #pragma unroll
        for (int ks = 0; ks < 17; ks++) {
            v8h a = *(const v8h*)&Ys[n*552 + ks*32 + quad*8];
            acc = __builtin_amdgcn_mfma_f32_16x16x32_f16(a, f3[ks], acc, 0, 0, 0);
        }
        #pragma unroll
        for (int r = 0; r < 4; r++)
            Crow[(quad*4 + r)*260 + 128 + w*16 + n] = acc[r];
    }
    // LN(128) of h -> Xs (2 rows per wave)
    #pragma unroll
    for (int rr = 0; rr < 2; rr++) {
        int r = w*2 + rr;
        float x0 = Hrow[r*132 + 2*lane], x1 = Hrow[r*132 + 2*lane + 1];
        float mu = waveAllSum(x0 + x1) * (1.f/128.f);
        float d0 = x0 - mu, d1 = x1 - mu;
        float var = waveAllSum(d0*d0 + d1*d1) * (1.f/128.f);
        float rs = rsqrtf(var + EPSLN);
        float2 gv = *(const float2*)&ls_g[2*lane];
        float2 bv = *(const float2*)&ls_b[2*lane];
        *(__half2*)&Xs[r*136 + 2*lane] = __floats2half2_rn(d0*rs*gv.x + bv.x, d1*rs*gv.y + bv.y);
    }
    __syncthreads();
    // t = relu(Xs @ ws1 + bs1)
    {
        float b0 = bs1[w*16 + n];
        v4f acc = (v4f){b0, b0, b0, b0};
        #pragma unroll
        for (int ks = 0; ks < 4; ks++) {
            v8h a = *(const v8h*)&Xs[n*136 + ks*32 + quad*8];
            acc = __builtin_amdgcn_mfma_f32_16x16x32_f16(a, fs1[ks], acc, 0, 0, 0);
        }
        #pragma unroll
        for (int r = 0; r < 4; r++)
            Ts[(quad*4 + r)*136 + w*16 + n] = (_Float16)fmaxf(acc[r], 0.f);
    }
    __syncthreads();
    // Crow[:,0:128] = h + t @ ws2 + bs2
    {
        float b0 = bs2[w*16 + n];
        v4f acc = (v4f){b0, b0, b0, b0};
        #pragma unroll
        for (int ks = 0; ks < 4; ks++) {
            v8h a = *(const v8h*)&Ts[n*136 + ks*32 + quad*8];
            acc = __builtin_amdgcn_mfma_f32_16x16x32_f16(a, fs2[ks], acc, 0, 0, 0);
        }
        #pragma unroll
        for (int r = 0; r < 4; r++) {
            int rr = quad*4 + r, col = w*16 + n;
            Crow[rr*260 + col] = Hrow[rr*132 + col] + acc[r];
        }
    }
    __syncthreads();
    // LN(256) -> Xa (2 rows per wave)
    #pragma unroll
    for (int rr = 0; rr < 2; rr++) {
        int r = w*2 + rr;
        float4 v = *(const float4*)&Crow[r*260 + 4*lane];
        float mu = waveAllSum(v.x + v.y + v.z + v.w) * (1.f/256.f);
        float d0 = v.x-mu, d1 = v.y-mu, d2 = v.z-mu, d3 = v.w-mu;
        float var = waveAllSum(d0*d0 + d1*d1 + d2*d2 + d3*d3) * (1.f/256.f);
        float rs = rsqrtf(var + EPSLN);
        float4 gv = *(const float4*)&g[4*lane];
        float4 bv = *(const float4*)&bb[4*lane];
        *(__half2*)&Xa[r*264 + 4*lane]     = __floats2half2_rn(d0*rs*gv.x + bv.x, d1*rs*gv.y + bv.y);
        *(__half2*)&Xa[r*264 + 4*lane + 2] = __floats2half2_rn(d2*rs*gv.z + bv.z, d3*rs*gv.w + bv.w);
    }
    __syncthreads();
    // u = relu(Xa @ wu1 + bu1)
    {
        float b0 = bu1[w*16 + n];
        v4f acc = (v4f){b0, b0, b0, b0};
        #pragma unroll
        for (int ks = 0; ks < 8; ks++) {
            v8h a = *(const v8h*)&Xa[n*264 + ks*32 + quad*8];
            acc = __builtin_amdgcn_mfma_f32_16x16x32_f16(a, f1[ks], acc, 0, 0, 0);
        }
        #pragma unroll
        for (int r = 0; r < 4; r++)
            Ut[(quad*4 + r)*136 + w*16 + n] = (_Float16)fmaxf(acc[r], 0.f);
    }
    __syncthreads();
    // hout = h + u @ wu2 + bu2
    {
        float b0 = bu2[w*16 + n];
        v4f acc = (v4f){b0, b0, b0, b0};
        #pragma unroll
        for (int ks = 0; ks < 4; ks++) {
            v8h a = *(const v8h*)&Ut[n*136 + ks*32 + quad*8];
            acc = __builtin_amdgcn_mfma_f32_16x16x32_f16(a, f2[ks], acc, 0, 0, 0);
        }
        #pragma unroll
        for (int r = 0; r < 4; r++) {
            int rr = quad*4 + r, col = w*16 + n;
            hout[(size_t)(row0 + rr)*128 + col] = Hrow[rr*132 + col] + acc[r];
        }
    }
}

// ---------- launch ----------
extern "C" void kernel_launch(void* const* d_in, const int* in_sizes, int n_in,
                              void* d_out, int out_size, void* d_ws, size_t ws_size,
                              hipStream_t stream) {
    const float* slots = (const float*)d_in[0];
    const float* ep    = (const float*)d_in[1];
    const float* et    = (const float*)d_in[2];
    const float* ls_g  = (const float*)d_in[3];
    const float* ls_b  = (const float*)d_in[4];
    const float* ws1   = (const float*)d_in[5];
    const float* bs1   = (const float*)d_in[6];
    const float* ws2   = (const float*)d_in[7];
    const float* bs2   = (const float*)d_in[8];
    const float* wi1   = (const float*)d_in[9];
    const float* bi1   = (const float*)d_in[10];
    const float* wi2   = (const float*)d_in[11];
    const float* bi2   = (const float*)d_in[12];
    const float* wi3   = (const float*)d_in[13];
    const float* bi3   = (const float*)d_in[14];
    const float* lu_g  = (const float*)d_in[15];
    const float* lu_b  = (const float*)d_in[16];
    const float* wu1   = (const float*)d_in[17];
    const float* bu1   = (const float*)d_in[18];
    const float* wu2   = (const float*)d_in[19];
    const float* bu2   = (const float*)d_in[20];
    float* out = (float*)d_out;

    char* p = (char*)d_ws;
    float*  h_buf   = (float*)p;   p += (size_t)NSLOT*DDIM*4;
    __half* Ycat    = (__half*)p;  p += (size_t)NSLOT*YROW*2;
    __half* wPre    = (__half*)p;  p += (size_t)TTYPE*BATCH*4096*2;
    __half* ws1T    = (__half*)p;  p += 128*128*2;
    __half* wi1catT = (__half*)p;  p += 1024*128*2;
    __half* ws2T    = (__half*)p;  p += 128*128*2;
    __half* wu1T    = (__half*)p;  p += 128*256*2;
    __half* wu2T    = (__half*)p;  p += 128*128*2;
    __half* w3catT  = (__half*)p;  p += 128*YROW*2;
    __half* w2T16   = (__half*)p;  p += 4*128*128*2;
    float*  biascat = (float*)p;   p += 1024*4;

    k_wconv<<<22 + 256, 256, 0, stream>>>(ws1, wi1, ws2, wu1, wu2, wi3, wi2, bi1, bi3,
                                          ep, et, ws1T, wi1catT, ws2T, wu1T, wu2T,
                                          w3catT, w2T16, biascat, wPre);

    for (int mp = 0; mp < 2; mp++) {
        const float* h = (mp == 0) ? slots : h_buf;
        float* hout = (mp == 0) ? h_buf : out;
        k_pair<<<BATCH*TTYPE, 512, 0, stream>>>(h, wi1catT, biascat, w2T16, bi2, wPre, Ycat);
        k_mega<<<NSLOT/16, 512, 0, stream>>>(Ycat, w3catT, ls_g, ls_b, ws1T, bs1, ws2T, bs2,
                                             lu_g, lu_b, wu1T, bu1, wu2T, bu2, h, hout);
    }
}